// Round 14
// baseline (653.317 us; speedup 1.0000x reference)
//
#include <hip/hip_runtime.h>
#include <math.h>

#define B_ 8
#define TN 512
#define DM 1024
#define H_ 16
#define DH 64
#define CACHED_ 2048
#define TT 2560

// 0.125 (1/sqrt(DH)) * log2(e): attention uses exp2 directly.
#define QSC 0.18033688011112042f
#define OHALF 4194304   // B*H*TN*DH  (f32 elems per split-half)
#define RHALF 65536     // B*H*TN

typedef __attribute__((ext_vector_type(8))) short bf16x8;
typedef __attribute__((ext_vector_type(4))) float f32x4;

union U16x8 { uint4 u; unsigned short s[8]; };
union U16x4 { uint2 u; unsigned short s[4]; };
union F4 { float4 v; float f[4]; };

__device__ __forceinline__ unsigned short f2b(float x) {
    unsigned u = __float_as_uint(x);
    unsigned r = (u + 0x7FFFu + ((u >> 16) & 1u)) >> 16;
    return (unsigned short)r;
}
__device__ __forceinline__ float b2f(unsigned short v) {
    return __uint_as_float((unsigned)v << 16);
}

// packed f32x2 -> bf16x2 RNE convert (single VALU op; no builtin on gfx950)
__device__ __forceinline__ unsigned cvt_pk_bf16(float lo, float hi) {
    unsigned r;
    asm("v_cvt_pk_bf16_f32 %0, %1, %2" : "=v"(r) : "v"(lo), "v"(hi));
    return r;
}

// async 16B global->LDS (width-16 variant; dest = wave-uniform base + lane*16)
__device__ __forceinline__ void gload16(const void* g, void* l) {
    __builtin_amdgcn_global_load_lds(
        (const __attribute__((address_space(1))) void*)g,
        (__attribute__((address_space(3))) void*)l, 16, 0, 0);
}

// ---------------------------------------------------------------------------
// Kernel A: fused f32->bf16 converts (blocks 0..4095) + per-batch counts /
// total_lengths (blocks 4096..4103). Both are dependency-free first-stage.
__global__ void cvt_all(const float* __restrict__ x,
                        const float* __restrict__ Wq,
                        const float* __restrict__ Wk,
                        const float* __restrict__ Wv,
                        const float* __restrict__ Wo,
                        unsigned short* __restrict__ Xbf,
                        unsigned short* __restrict__ Wqkvb,
                        unsigned short* __restrict__ Wob,
                        const unsigned char* __restrict__ vnm,
                        const unsigned char* __restrict__ kpm,
                        const int* __restrict__ past_len,
                        int* __restrict__ counts,
                        float* __restrict__ total_out) {
    if (blockIdx.x >= 4096) {
        // count path (8 blocks, one per batch item)
        int b = blockIdx.x - 4096;
        __shared__ int red[256];
        int esz = (kpm[1] | kpm[2] | kpm[3]) ? 1 : 4;  // bool vs int32
        int s = 0;
        for (int t = threadIdx.x; t < TN; t += 256)
            s += (vnm[(size_t)(b * TN + t) * esz] != 0) ? 1 : 0;
        red[threadIdx.x] = s;
        __syncthreads();
        for (int off = 128; off > 0; off >>= 1) {
            if (threadIdx.x < off) red[threadIdx.x] += red[threadIdx.x + off];
            __syncthreads();
        }
        if (threadIdx.x == 0) {
            counts[b] = red[0];
            total_out[b] = (float)(past_len[b] + red[0]);
        }
        return;
    }
    int i8 = (blockIdx.x * 256 + threadIdx.x) << 3;  // [0, 8M)
    const float* src;
    unsigned short* dst;
    int off;
    if (i8 < (1 << 22)) {
        src = x; off = i8; dst = Xbf + i8;
    } else if (i8 < (1 << 22) + (3 << 20)) {
        int j = i8 - (1 << 22);
        int w = j >> 20;
        src = w == 0 ? Wq : (w == 1 ? Wk : Wv);
        off = j & 0xFFFFF;
        dst = Wqkvb + j;
    } else {
        int j = i8 - ((1 << 22) + (3 << 20));
        src = Wo; off = j; dst = Wob + j;
    }
    float4 a = *(const float4*)(src + off);
    float4 b = *(const float4*)(src + off + 4);
    U16x8 o;
    o.s[0] = f2b(a.x); o.s[1] = f2b(a.y); o.s[2] = f2b(a.z); o.s[3] = f2b(a.w);
    o.s[4] = f2b(b.x); o.s[5] = f2b(b.y); o.s[6] = f2b(b.z); o.s[7] = f2b(b.w);
    *(uint4*)dst = o.u;
}

// ---------------------------------------------------------------------------
// Shared MFMA GEMM core: C(128x128) = A[M,K] * Bw[N,K]^T, bf16 in, f32 acc.
// Single-barrier 2-phase K pipeline (harness-verified R11).
__device__ __forceinline__ void gemm_core(
    const unsigned short* __restrict__ A, const unsigned short* __restrict__ Bw,
    int K, int m0, int n0, short* As2, short* Bs2, f32x4 acc[4][4]) {
    const int tid = threadIdx.x;
    const int wave = tid >> 6, lane = tid & 63;
    const int wm = wave >> 1, wn = wave & 1;
    const int l15 = lane & 15, lq = lane >> 4;

    // staging: per call a wave fills 16 rows x 32 cols (1 KiB). lane l covers
    // row wave*16 + (l>>2), elems (l&3)*8 -- matches HW dest base + l*16B.
    const int srow = wave * 16 + (lane >> 2);
    const int sc = (lane & 3) << 3;
    const unsigned short* Ag0 = A + (size_t)(m0 + srow) * K + sc;
    const unsigned short* Ag1 = A + (size_t)(m0 + 64 + srow) * K + sc;
    const unsigned short* Bg0 = Bw + (size_t)(n0 + srow) * K + sc;
    const unsigned short* Bg1 = Bw + (size_t)(n0 + 64 + srow) * K + sc;
    const int d0 = wave * 512;          // shorts offset within one buffer
    const int d1 = 2048 + wave * 512;   // (64 + wave*16) * 32

    // prologue: prefetch K-tile 0 into buffer 0
    gload16(Ag0, As2 + d0);
    gload16(Ag1, As2 + d1);
    gload16(Bg0, Bs2 + d0);
    gload16(Bg1, Bs2 + d1);

    int cur = 0;
    for (int k0 = 0; k0 < K; k0 += 32) {
        // buf[cur] DMA complete (everyone's); all waves done reading buf[cur^1]
        asm volatile("s_waitcnt vmcnt(0)" ::: "memory");
        __builtin_amdgcn_s_barrier();

        // prefetch next K-tile (clamped on last iter; redundant load harmless)
        int kn = (k0 + 32 < K) ? k0 + 32 : k0;
        short* An = As2 + ((cur ^ 1) << 12);
        short* Bn = Bs2 + ((cur ^ 1) << 12);
        gload16(Ag0 + kn, An + d0);
        gload16(Ag1 + kn, An + d1);
        gload16(Bg0 + kn, Bn + d0);
        gload16(Bg1 + kn, Bn + d1);

        const short* Ac = As2 + (cur << 12);
        const short* Bc = Bs2 + (cur << 12);
        bf16x8 af[4], bf[4];
#pragma unroll
        for (int mi = 0; mi < 4; ++mi)
            af[mi] = *(const bf16x8*)&Ac[(wm * 64 + mi * 16 + l15) * 32 + lq * 8];
#pragma unroll
        for (int ni = 0; ni < 4; ++ni)
            bf[ni] = *(const bf16x8*)&Bc[(wn * 64 + ni * 16 + l15) * 32 + lq * 8];
#pragma unroll
        for (int mi = 0; mi < 4; ++mi)
#pragma unroll
            for (int ni = 0; ni < 4; ++ni)
                acc[mi][ni] = __builtin_amdgcn_mfma_f32_16x16x32_bf16(
                    af[mi], bf[ni], acc[mi][ni], 0, 0, 0);
        cur ^= 1;
    }
}

// Kernel 1: QKV projection -> bf16 Qraw/Kraw/Vraw in [B,H,TN,DH].
// RoPE (+ the 0.125*log2e attention scale) folded into the Q epilogue.
__global__ __launch_bounds__(256) void gemm_qkv_mfma(
    const unsigned short* __restrict__ Xbf,
    const unsigned short* __restrict__ Wqkv,
    const float* __restrict__ bq, const float* __restrict__ bk,
    const float* __restrict__ bv, const float* __restrict__ inv_freq,
    const int* __restrict__ past_len,
    unsigned short* __restrict__ Qraw, unsigned short* __restrict__ Kraw,
    unsigned short* __restrict__ Vraw) {
    __shared__ __align__(16) short As[2 * 128 * 32];
    __shared__ __align__(16) short Bs[2 * 128 * 32];
    f32x4 acc[4][4] = {};
    const int m0 = blockIdx.y << 7, n0 = blockIdx.x << 7;
    gemm_core(Xbf, Wqkv, DM, m0, n0, As, Bs, acc);

    const int which = n0 >> 10;
    const int tid = threadIdx.x, wave = tid >> 6, lane = tid & 63;
    const int wm = wave >> 1, wn = wave & 1, l15 = lane & 15, lq = lane >> 4;

    if (which == 0) {
        // Q path with fused RoPE. 128-row tile sits in a single batch item.
        const int bb = m0 >> 9;
        const int pl = past_len[bb];
        const int hh = (n0 + wn * 64) >> 6;
#pragma unroll
        for (int ni = 0; ni < 2; ++ni) {
            int i = ni * 16 + l15;          // dh_lo in [0,32)
            int n1 = n0 + wn * 64 + ni * 16 + l15;
            float fi = inv_freq[i];
            float blo = bq[n1], bhi = bq[n1 + 32];
#pragma unroll
            for (int mi = 0; mi < 4; ++mi) {
#pragma unroll
                for (int r = 0; r < 4; ++r) {
                    int m = m0 + wm * 64 + mi * 16 + lq * 4 + r;
                    int t = m & 511;
                    float ang = (float)(pl + t) * fi;
                    float s, c;
                    __sincosf(ang, &s, &c);
                    float x1 = acc[mi][ni][r] + blo;
                    float x2 = acc[mi][ni + 2][r] + bhi;
                    size_t base = ((size_t)(bb * H_ + hh) * TN + t) * DH;
                    Qraw[base + i]      = f2b((x1 * c - x2 * s) * QSC);
                    Qraw[base + i + 32] = f2b((x2 * c + x1 * s) * QSC);
                }
            }
        }
    } else {
        const float* bias = which == 1 ? bk : bv;
        unsigned short* dst = which == 1 ? Kraw : Vraw;
#pragma unroll
        for (int ni = 0; ni < 4; ++ni) {
            int n1 = (n0 & 1023) + wn * 64 + ni * 16 + l15;
            float bb = bias[n1];
            int h = n1 >> 6, dh = n1 & 63;
#pragma unroll
            for (int mi = 0; mi < 4; ++mi) {
#pragma unroll
                for (int r = 0; r < 4; ++r) {
                    int m = m0 + wm * 64 + mi * 16 + lq * 4 + r;
                    int b = m >> 9, t = m & 511;
                    dst[((size_t)(b * H_ + h) * TN + t) * DH + dh] =
                        f2b(acc[mi][ni][r] + bb);
                }
            }
        }
    }
}

// Kernel 4: output projection, masked rows -> 0, f32 out.
__global__ __launch_bounds__(256) void gemm_out_mfma(
    const unsigned short* __restrict__ Ctxb,
    const unsigned short* __restrict__ Wob,
    const float* __restrict__ bo, const int* __restrict__ counts,
    float* __restrict__ Out) {
    __shared__ __align__(16) short As[2 * 128 * 32];
    __shared__ __align__(16) short Bs[2 * 128 * 32];
    f32x4 acc[4][4] = {};
    const int m0 = blockIdx.y << 7, n0 = blockIdx.x << 7;
    gemm_core(Ctxb, Wob, DM, m0, n0, As, Bs, acc);

    const int tid = threadIdx.x, wave = tid >> 6, lane = tid & 63;
    const int wm = wave >> 1, wn = wave & 1, l15 = lane & 15, lq = lane >> 4;
    const int cnt = counts[m0 >> 9];  // block-uniform batch item
#pragma unroll
    for (int mi = 0; mi < 4; ++mi) {
#pragma unroll
        for (int r = 0; r < 4; ++r) {
            int m = m0 + wm * 64 + mi * 16 + lq * 4 + r;
            int t = m & 511;
            bool valid = t < cnt;
#pragma unroll
            for (int ni = 0; ni < 4; ++ni) {
                int n = n0 + wn * 64 + ni * 16 + l15;
                Out[(size_t)m * DM + n] = valid ? acc[mi][ni][r] + bo[n] : 0.f;
            }
        }
    }
}

// ---------------------------------------------------------------------------
// Kernel 2b: build k_total / v_total (f32 outputs) + bf16 copies. Vectorized:
// 8 threads per position, each owns dh quads {4i..4i+3, 4i+32..4i+35}.
__global__ void build_kv(const float* __restrict__ past_k,
                         const float* __restrict__ past_v,
                         const unsigned short* __restrict__ Kraw,
                         const unsigned short* __restrict__ Vraw,
                         const float* __restrict__ inv_freq,
                         const int* __restrict__ past_len,
                         const int* __restrict__ counts,
                         float* __restrict__ Ko, float* __restrict__ Vo,
                         unsigned short* __restrict__ Kb16,
                         unsigned short* __restrict__ Vb16) {
    int idx = blockIdx.x * 256 + threadIdx.x;  // TT*8
    int i = idx & 7;
    int p = idx >> 3;
    int h = blockIdx.y, bz = blockIdx.z;
    int pl = past_len[bz], cnt = counts[bz];
    int dh = i << 2;
    size_t obase = ((size_t)(bz * H_ + h) * TT + p) * DH;
    F4 k1, k2, v1, v2;
    if (p < pl) {
        size_t ib = ((size_t)(bz * H_ + h) * CACHED_ + p) * DH;
        k1.v = *(const float4*)(past_k + ib + dh);
        k2.v = *(const float4*)(past_k + ib + dh + 32);
        v1.v = *(const float4*)(past_v + ib + dh);
        v2.v = *(const float4*)(past_v + ib + dh + 32);
    } else if (p < pl + cnt) {
        int t = p - pl;
        size_t ib = ((size_t)(bz * H_ + h) * TN + t) * DH;
        U16x4 ka, kc, va, vc;
        ka.u = *(const uint2*)(Kraw + ib + dh);
        kc.u = *(const uint2*)(Kraw + ib + dh + 32);
        va.u = *(const uint2*)(Vraw + ib + dh);
        vc.u = *(const uint2*)(Vraw + ib + dh + 32);
#pragma unroll
        for (int j = 0; j < 4; ++j) {
            float ang = (float)p * inv_freq[dh + j];
            float s, c;
            __sincosf(ang, &s, &c);
            float x1 = b2f(ka.s[j]), x2 = b2f(kc.s[j]);
            k1.f[j] = x1 * c - x2 * s;
            k2.f[j] = x2 * c + x1 * s;
            v1.f[j] = b2f(va.s[j]);
            v2.f[j] = b2f(vc.s[j]);
        }
    } else {
        k1.v = k2.v = v1.v = v2.v = make_float4(0.f, 0.f, 0.f, 0.f);
    }
    *(float4*)(Ko + obase + dh) = k1.v;
    *(float4*)(Ko + obase + dh + 32) = k2.v;
    *(float4*)(Vo + obase + dh) = v1.v;
    *(float4*)(Vo + obase + dh + 32) = v2.v;
    U16x4 o;
#pragma unroll
    for (int j = 0; j < 4; ++j) o.s[j] = f2b(k1.f[j]);
    *(uint2*)(Kb16 + obase + dh) = o.u;
#pragma unroll
    for (int j = 0; j < 4; ++j) o.s[j] = f2b(k2.f[j]);
    *(uint2*)(Kb16 + obase + dh + 32) = o.u;
#pragma unroll
    for (int j = 0; j < 4; ++j) o.s[j] = f2b(v1.f[j]);
    *(uint2*)(Vb16 + obase + dh) = o.u;
#pragma unroll
    for (int j = 0; j < 4; ++j) o.s[j] = f2b(v2.f[j]);
    *(uint2*)(Vb16 + obase + dh + 32) = o.u;
}

// ---------------------------------------------------------------------------
// Kernel 3a: split-K MFMA flash attention. 512 threads (8 waves), QBLK=128,
// 2 blocks per (b,h,qt) -- each covers half the KV-tile range. Because the
// softmax is no-max (P = exp2(S)), partials are exactly additive: each block
// writes f32 O_partial + rsum_partial; attn_merge combines them.
// Occupancy levers vs R13 (Occupancy was 22%): __launch_bounds__(512,8)
// forces VGPR<=64 (wave cap 8/SIMD) and the P buffer aliases the dead-after-
// prologue Q staging buffer (LDS 56->40KB) -> capacity 4 blocks/CU; grid
// 1024 blocks = 4/CU resident, double the resident waves.
// R11-verified inner loop otherwise (2 barriers, 2-phase K, cvt_pk P store).
__global__ __launch_bounds__(512, 8) void attn_split(
    const unsigned short* __restrict__ Qbf,   // [B,H,TN,DH] bf16 (roped*QSC)
    const unsigned short* __restrict__ Kb,    // [B,H,TT,DH] bf16
    const unsigned short* __restrict__ Vb,    // [B,H,TT,DH] bf16
    const int* __restrict__ past_len, const int* __restrict__ counts,
    float* __restrict__ Opart,                // [2][B,H,TN,DH] f32
    float* __restrict__ Rpart) {              // [2][B,H,TN] f32
    // decode: j = xcd + 8*(sub + 8*pg), sub = half*4+qt  [bijective over 1024]
    const int j = blockIdx.x;
    const int xcd = j & 7;
    const int sub = (j >> 3) & 7;
    const int qt = sub & 3;
    const int half = sub >> 2;
    const int pg = j >> 6;                    // [0,16)
    const int p = pg * 8 + xcd;               // (b,h) pair in [0,128)
    const int b = p >> 4, h = p & 15;

    const int tid = threadIdx.x;              // [0,512)
    const int wave = tid >> 6, lane = tid & 63;
    const int l15 = lane & 15, lq = lane >> 4;

    __shared__ __align__(16) short Ks[2][4096];   // 2 x (64 x 64)
    __shared__ __align__(16) short Vt[4096];      // 64dh x 64k transposed
    __shared__ __align__(16) short PQ[8192];      // Q staging, then P (aliased)

    const size_t qbase = ((size_t)(b * H_ + h) * TN + qt * 128) * DH;
    const size_t kbase = (size_t)(b * H_ + h) * TT * DH;

    const int total = past_len[b] + counts[b];
    const int ntiles = (total + 63) >> 6;
    const int nth = (ntiles + 1) >> 1;        // tiles per half (ceil)
    const int kt0 = half * nth;
    const int kt1 = (kt0 + nth < ntiles) ? kt0 + nth : ntiles;

    // async K staging: 512 dest chunks, 1/thread. dest chunk d -> src:
    // g=d>>7, c=(d>>4)&7, row=g*16+((d&15)^c), col=c*8
    const int dA = tid;
    const int krA = (dA >> 7) * 16 + ((dA & 15) ^ ((dA >> 4) & 7));
    const int kcA = ((dA >> 4) & 7) << 3;
    const unsigned short* KgA = Kb + kbase + (size_t)krA * DH + kcA;
    const int kdoffA = wave * 512;            // wave-uniform LDS short-offset

    // prefetch K tile kt0 (latency covered by Q staging below)
    gload16(KgA + (size_t)kt0 * 64 * DH, &Ks[0][kdoffA]);

    // V: thread owns keys {2kp,2kp+1} x 4 dh values (uint2 loads)
    const int kp = tid & 31;
    const int dh4 = (tid >> 5) << 2;          // [0,64) step 4
    const int kc = kp >> 2, ko2 = (kp & 3) << 1;
    const unsigned short* Vg = Vb + kbase + (size_t)(2 * kp) * DH + dh4;
    uint2 vr0 = *(const uint2*)(Vg + (size_t)kt0 * 64 * DH);
    uint2 vr1 = *(const uint2*)(Vg + (size_t)kt0 * 64 * DH + DH);

    // stage Q into PQ (swizzled, one-time; PQ is reused for P afterwards)
#pragma unroll
    for (int jj = 0; jj < 2; ++jj) {
        int e = tid + (jj << 9);
        int row = e >> 3, c = e & 7;
        *(uint4*)&PQ[(((row >> 4) * 8 + c) * 16 + ((row & 15) ^ c)) * 8] =
            *(const uint4*)(Qbf + qbase + row * 64 + c * 8);
    }
    __syncthreads();   // prologue: publishes Q; drains K(kt0)/V(kt0)
    const int c0 = lq, c1 = 4 + lq;
    bf16x8 qa0 = *(const bf16x8*)&PQ[((wave * 8 + c0) * 16 + (l15 ^ c0)) * 8];
    bf16x8 qa1 = *(const bf16x8*)&PQ[((wave * 8 + c1) * 16 + (l15 ^ c1)) * 8];
    // Q fragments now in regs; PQ becomes the per-wave P buffer. The first
    // P write happens only after all waves pass tile kt0's barriers.

    float rsum[4] = {0.f, 0.f, 0.f, 0.f};
    f32x4 O[4] = {};
    unsigned short* Pw = (unsigned short*)(PQ + wave * 1024);
    const int pc0 = l15 >> 3, pwo = l15 & 7;

    int cur = 0;
    for (int kt = kt0; kt < kt1; ++kt) {
        // --- barrier A: prefetched K(kt)+V(kt) complete; all waves done
        //     reading previous tile's Ks[cur^1] and Vt.
        asm volatile("s_waitcnt vmcnt(0)" ::: "memory");
        __builtin_amdgcn_s_barrier();

        // V(kt) regs -> Vt (swizzled transpose write, 4 dh per thread)
        {
            U16x4 a, cc;
            a.u = vr0;
            cc.u = vr1;
#pragma unroll
            for (int jj = 0; jj < 4; ++jj) {
                int dh = dh4 + jj;
                unsigned pk = (unsigned)a.s[jj] | ((unsigned)cc.s[jj] << 16);
                *(unsigned*)&Vt[((((dh >> 4) * 8 + kc) * 16) + ((dh & 15) ^ kc)) * 8 + ko2] = pk;
            }
        }
        // prefetch tile kt+1 (clamped): K -> Ks[cur^1] (async LDS),
        // V -> regs. In flight across the whole compute phase below.
        {
            int ktn = (kt + 1 < kt1) ? kt + 1 : kt;
            gload16(KgA + (size_t)ktn * 64 * DH, &Ks[cur ^ 1][kdoffA]);
            vr0 = *(const uint2*)(Vg + (size_t)ktn * 64 * DH);
            vr1 = *(const uint2*)(Vg + (size_t)ktn * 64 * DH + DH);
        }

        // --- barrier D: publish V ds_writes; do NOT drain vmem prefetch.
        asm volatile("s_waitcnt lgkmcnt(0)" ::: "memory");
        __builtin_amdgcn_s_barrier();
        __builtin_amdgcn_sched_barrier(0);

        // S = Q K^T from Ks[cur] (scale + log2e pre-folded into Q)
        const short* Kcur = Ks[cur];
        f32x4 S[4];
#pragma unroll
        for (int nt = 0; nt < 4; ++nt) {
            f32x4 acc = {};
            bf16x8 kb0 = *(const bf16x8*)&Kcur[((nt * 8 + c0) * 16 + (l15 ^ c0)) * 8];
            acc = __builtin_amdgcn_mfma_f32_16x16x32_bf16(qa0, kb0, acc, 0, 0, 0);
            bf16x8 kb1 = *(const bf16x8*)&Kcur[((nt * 8 + c1) * 16 + (l15 ^ c1)) * 8];
            acc = __builtin_amdgcn_mfma_f32_16x16x32_bf16(qa1, kb1, acc, 0, 0, 0);
            S[nt] = acc;
        }

        // mask only the (uniform) last partial tile
        int limit = total - (kt << 6);
        if (limit < 64) {
#pragma unroll
            for (int nt = 0; nt < 4; ++nt) {
                bool ok = nt * 16 + l15 < limit;
#pragma unroll
                for (int r = 0; r < 4; ++r) S[nt][r] = ok ? S[nt][r] : -1e30f;
            }
        }

        // P = exp2(S); per-lane partial row sums; bf16 P via cvt_pk pairs.
#pragma unroll
        for (int nt = 0; nt < 4; ++nt) {
            const int pc = nt * 2 + pc0;
#pragma unroll
            for (int rr = 0; rr < 2; ++rr) {
                float p0 = __builtin_amdgcn_exp2f(S[nt][2 * rr]);
                float p1 = __builtin_amdgcn_exp2f(S[nt][2 * rr + 1]);
                rsum[2 * rr] += p0;
                rsum[2 * rr + 1] += p1;
                unsigned pk = cvt_pk_bf16(p0, p1);
                int row0 = lq * 4 + 2 * rr;
                int row1 = row0 + 1;
                Pw[(pc * 16 + (row0 ^ pc)) * 8 + pwo] = (unsigned short)pk;
                Pw[(pc * 16 + (row1 ^ pc)) * 8 + pwo] = (unsigned short)(pk >> 16);
            }
        }
        asm volatile("s_waitcnt lgkmcnt(0)" ::: "memory");

        // O += P V
        bf16x8 pa0 = *(const bf16x8*)&Pw[(c0 * 16 + (l15 ^ c0)) * 8];
        bf16x8 pa1 = *(const bf16x8*)&Pw[(c1 * 16 + (l15 ^ c1)) * 8];
#pragma unroll
        for (int nt = 0; nt < 4; ++nt) {
            bf16x8 vb0 = *(const bf16x8*)&Vt[((nt * 8 + c0) * 16 + (l15 ^ c0)) * 8];
            O[nt] = __builtin_amdgcn_mfma_f32_16x16x32_bf16(pa0, vb0, O[nt], 0, 0, 0);
            bf16x8 vb1 = *(const bf16x8*)&Vt[((nt * 8 + c1) * 16 + (l15 ^ c1)) * 8];
            O[nt] = __builtin_amdgcn_mfma_f32_16x16x32_bf16(pa1, vb1, O[nt], 0, 0, 0);
        }
        cur ^= 1;
    }

    // one-time l reduction across the 16 key-lanes
#pragma unroll
    for (int off = 1; off < 16; off <<= 1)
#pragma unroll
        for (int r = 0; r < 4; ++r) rsum[r] += __shfl_xor(rsum[r], off);

    // epilogue: write f32 partials (no divide; merge kernel combines)
    float* Od = Opart + (size_t)half * OHALF;
    float* Rd = Rpart + (size_t)half * RHALF;
#pragma unroll
    for (int r = 0; r < 4; ++r) {
        int t = qt * 128 + wave * 16 + lq * 4 + r;
        size_t obase = ((size_t)(b * H_ + h) * TN + t) * DH;
#pragma unroll
        for (int nt = 0; nt < 4; ++nt)
            Od[obase + nt * 16 + l15] = O[nt][r];
        if (l15 == 0) Rd[(size_t)(b * H_ + h) * TN + t] = rsum[r];
    }
}

// Kernel 3b: merge split-K partials -> bf16 Ctxb [B,TN,DM].
__global__ __launch_bounds__(256) void attn_merge(
    const float* __restrict__ Opart, const float* __restrict__ Rpart,
    unsigned short* __restrict__ Ctxb) {
    int idx = blockIdx.x * 256 + threadIdx.x;  // B*H*TN*8 = 524288
    int i8 = idx & 7;
    int row = idx >> 3;                        // (b*H+h)*TN + t
    int dh8 = i8 << 3;
    const float* O0 = Opart + (size_t)row * DH + dh8;
    const float* O1 = O0 + OHALF;
    float inv = 1.f / (Rpart[row] + Rpart[RHALF + row]);
    int t = row & 511, bh = row >> 9;
    int h = bh & 15, b = bh >> 4;
    F4 a0, a1, c0, c1;
    a0.v = *(const float4*)O0;
    a1.v = *(const float4*)(O0 + 4);
    c0.v = *(const float4*)O1;
    c1.v = *(const float4*)(O1 + 4);
    U16x8 o;
#pragma unroll
    for (int jj = 0; jj < 4; ++jj) o.s[jj] = f2b((a0.f[jj] + c0.f[jj]) * inv);
#pragma unroll
    for (int jj = 0; jj < 4; ++jj) o.s[4 + jj] = f2b((a1.f[jj] + c1.f[jj]) * inv);
    *(uint4*)(Ctxb + ((size_t)(b * TN + t)) * DM + h * 64 + dh8) = o.u;
}

// ---------------------------------------------------------------------------
extern "C" void kernel_launch(void* const* d_in, const int* in_sizes, int n_in,
                              void* d_out, int out_size, void* d_ws, size_t ws_size,
                              hipStream_t stream) {
    const float* x_new    = (const float*)d_in[0];
    const float* inv_freq = (const float*)d_in[1];
    const float* past_k   = (const float*)d_in[2];
    const float* past_v   = (const float*)d_in[3];
    const float* Wq = (const float*)d_in[4];
    const float* bq = (const float*)d_in[5];
    const float* Wk = (const float*)d_in[6];
    const float* bk = (const float*)d_in[7];
    const float* Wv = (const float*)d_in[8];
    const float* bv = (const float*)d_in[9];
    const float* Wo = (const float*)d_in[10];
    const float* bo = (const float*)d_in[11];
    const unsigned char* kpm = (const unsigned char*)d_in[12];
    const int* past_len      = (const int*)d_in[13];
    const unsigned char* vnm = (const unsigned char*)d_in[14];

    float* out      = (float*)d_out;                         // [B,TN,DM]
    float* k_total  = out + (size_t)B_ * TN * DM;            // [B,H,TT,DH]
    float* v_total  = k_total + (size_t)B_ * H_ * TT * DH;
    float* total_out = v_total + (size_t)B_ * H_ * TT * DH;  // [B] (float)

    const size_t NQ = (size_t)B_ * TN * DM;        // 4M
    const size_t NKV = (size_t)B_ * H_ * TT * DH;  // 21M

    int* counts = (int*)d_ws;
    unsigned short* Xbf   = (unsigned short*)((char*)d_ws + 256);  // [4096,1024]
    unsigned short* Wqkvb = Xbf + NQ;                              // [3072,1024]
    unsigned short* Wob   = Wqkvb + (size_t)3 * DM * DM;           // [1024,1024]
    unsigned short* Qraw  = Wob + (size_t)DM * DM;                 // [B,H,TN,DH]
    unsigned short* Kraw  = Qraw + NQ;
    unsigned short* Vraw  = Kraw + NQ;
    unsigned short* Ctxb  = Vraw + NQ;                             // [B,TN,DM]
    unsigned short* Kb16  = Ctxb + NQ;                             // [B,H,TT,DH]
    unsigned short* Vb16  = Kb16 + NKV;
    float* Opart = (float*)(Vb16 + NKV);           // [2][B,H,TN,DH] f32
    float* Rpart = Opart + 2 * (size_t)OHALF;      // [2][B,H,TN] f32

    cvt_all<<<4104, 256, 0, stream>>>(x_new, Wq, Wk, Wv, Wo, Xbf, Wqkvb, Wob,
                                      vnm, kpm, past_len, counts, total_out);

    gemm_qkv_mfma<<<dim3(24, 32), 256, 0, stream>>>(
        Xbf, Wqkvb, bq, bk, bv, inv_freq, past_len, Qraw, Kraw, Vraw);
    build_kv<<<dim3((TT * 8) / 256, H_, B_), 256, 0, stream>>>(
        past_k, past_v, Kraw, Vraw, inv_freq, past_len, counts,
        k_total, v_total, Kb16, Vb16);
    attn_split<<<1024, 512, 0, stream>>>(Qraw, Kb16, Vb16,
                                         past_len, counts, Opart, Rpart);
    attn_merge<<<(B_ * H_ * TN * 8) / 256, 256, 0, stream>>>(Opart, Rpart, Ctxb);
    gemm_out_mfma<<<dim3(8, 32), 256, 0, stream>>>(Ctxb, Wob, bo, counts, out);
}

// Round 15
// 492.609 us; speedup vs baseline: 1.3262x; 1.3262x over previous
//
#include <hip/hip_runtime.h>
#include <math.h>

#define B_ 8
#define TN 512
#define DM 1024
#define H_ 16
#define DH 64
#define CACHED_ 2048
#define TT 2560

// 0.125 (1/sqrt(DH)) * log2(e): attention uses exp2 directly.
#define QSC 0.18033688011112042f

typedef __attribute__((ext_vector_type(8))) short bf16x8;
typedef __attribute__((ext_vector_type(4))) float f32x4;

union U16x8 { uint4 u; unsigned short s[8]; };
union U16x4 { uint2 u; unsigned short s[4]; };
union F4 { float4 v; float f[4]; };

__device__ __forceinline__ unsigned short f2b(float x) {
    unsigned u = __float_as_uint(x);
    unsigned r = (u + 0x7FFFu + ((u >> 16) & 1u)) >> 16;
    return (unsigned short)r;
}
__device__ __forceinline__ float b2f(unsigned short v) {
    return __uint_as_float((unsigned)v << 16);
}

// packed f32x2 -> bf16x2 RNE convert (single VALU op; no builtin on gfx950)
__device__ __forceinline__ unsigned cvt_pk_bf16(float lo, float hi) {
    unsigned r;
    asm("v_cvt_pk_bf16_f32 %0, %1, %2" : "=v"(r) : "v"(lo), "v"(hi));
    return r;
}

// async 16B global->LDS (width-16 variant; dest = wave-uniform base + lane*16)
__device__ __forceinline__ void gload16(const void* g, void* l) {
    __builtin_amdgcn_global_load_lds(
        (const __attribute__((address_space(1))) void*)g,
        (__attribute__((address_space(3))) void*)l, 16, 0, 0);
}

// ---------------------------------------------------------------------------
// Kernel A: fused f32->bf16 converts (blocks 0..4095) + per-batch counts /
// total_lengths (blocks 4096..4103). Both are dependency-free first-stage.
__global__ void cvt_all(const float* __restrict__ x,
                        const float* __restrict__ Wq,
                        const float* __restrict__ Wk,
                        const float* __restrict__ Wv,
                        const float* __restrict__ Wo,
                        unsigned short* __restrict__ Xbf,
                        unsigned short* __restrict__ Wqkvb,
                        unsigned short* __restrict__ Wob,
                        const unsigned char* __restrict__ vnm,
                        const unsigned char* __restrict__ kpm,
                        const int* __restrict__ past_len,
                        int* __restrict__ counts,
                        float* __restrict__ total_out) {
    if (blockIdx.x >= 4096) {
        // count path (8 blocks, one per batch item)
        int b = blockIdx.x - 4096;
        __shared__ int red[256];
        int esz = (kpm[1] | kpm[2] | kpm[3]) ? 1 : 4;  // bool vs int32
        int s = 0;
        for (int t = threadIdx.x; t < TN; t += 256)
            s += (vnm[(size_t)(b * TN + t) * esz] != 0) ? 1 : 0;
        red[threadIdx.x] = s;
        __syncthreads();
        for (int off = 128; off > 0; off >>= 1) {
            if (threadIdx.x < off) red[threadIdx.x] += red[threadIdx.x + off];
            __syncthreads();
        }
        if (threadIdx.x == 0) {
            counts[b] = red[0];
            total_out[b] = (float)(past_len[b] + red[0]);
        }
        return;
    }
    int i8 = (blockIdx.x * 256 + threadIdx.x) << 3;  // [0, 8M)
    const float* src;
    unsigned short* dst;
    int off;
    if (i8 < (1 << 22)) {
        src = x; off = i8; dst = Xbf + i8;
    } else if (i8 < (1 << 22) + (3 << 20)) {
        int j = i8 - (1 << 22);
        int w = j >> 20;
        src = w == 0 ? Wq : (w == 1 ? Wk : Wv);
        off = j & 0xFFFFF;
        dst = Wqkvb + j;
    } else {
        int j = i8 - ((1 << 22) + (3 << 20));
        src = Wo; off = j; dst = Wob + j;
    }
    float4 a = *(const float4*)(src + off);
    float4 b = *(const float4*)(src + off + 4);
    U16x8 o;
    o.s[0] = f2b(a.x); o.s[1] = f2b(a.y); o.s[2] = f2b(a.z); o.s[3] = f2b(a.w);
    o.s[4] = f2b(b.x); o.s[5] = f2b(b.y); o.s[6] = f2b(b.z); o.s[7] = f2b(b.w);
    *(uint4*)dst = o.u;
}

// ---------------------------------------------------------------------------
// Shared MFMA GEMM core: C(128x128) = A[M,K] * Bw[N,K]^T, bf16 in, f32 acc.
// Single-barrier 2-phase K pipeline (harness-verified R11).
__device__ __forceinline__ void gemm_core(
    const unsigned short* __restrict__ A, const unsigned short* __restrict__ Bw,
    int K, int m0, int n0, short* As2, short* Bs2, f32x4 acc[4][4]) {
    const int tid = threadIdx.x;
    const int wave = tid >> 6, lane = tid & 63;
    const int wm = wave >> 1, wn = wave & 1;
    const int l15 = lane & 15, lq = lane >> 4;

    // staging: per call a wave fills 16 rows x 32 cols (1 KiB). lane l covers
    // row wave*16 + (l>>2), elems (l&3)*8 -- matches HW dest base + l*16B.
    const int srow = wave * 16 + (lane >> 2);
    const int sc = (lane & 3) << 3;
    const unsigned short* Ag0 = A + (size_t)(m0 + srow) * K + sc;
    const unsigned short* Ag1 = A + (size_t)(m0 + 64 + srow) * K + sc;
    const unsigned short* Bg0 = Bw + (size_t)(n0 + srow) * K + sc;
    const unsigned short* Bg1 = Bw + (size_t)(n0 + 64 + srow) * K + sc;
    const int d0 = wave * 512;          // shorts offset within one buffer
    const int d1 = 2048 + wave * 512;   // (64 + wave*16) * 32

    // prologue: prefetch K-tile 0 into buffer 0
    gload16(Ag0, As2 + d0);
    gload16(Ag1, As2 + d1);
    gload16(Bg0, Bs2 + d0);
    gload16(Bg1, Bs2 + d1);

    int cur = 0;
    for (int k0 = 0; k0 < K; k0 += 32) {
        // buf[cur] DMA complete (everyone's); all waves done reading buf[cur^1]
        asm volatile("s_waitcnt vmcnt(0)" ::: "memory");
        __builtin_amdgcn_s_barrier();

        // prefetch next K-tile (clamped on last iter; redundant load harmless)
        int kn = (k0 + 32 < K) ? k0 + 32 : k0;
        short* An = As2 + ((cur ^ 1) << 12);
        short* Bn = Bs2 + ((cur ^ 1) << 12);
        gload16(Ag0 + kn, An + d0);
        gload16(Ag1 + kn, An + d1);
        gload16(Bg0 + kn, Bn + d0);
        gload16(Bg1 + kn, Bn + d1);

        const short* Ac = As2 + (cur << 12);
        const short* Bc = Bs2 + (cur << 12);
        bf16x8 af[4], bf[4];
#pragma unroll
        for (int mi = 0; mi < 4; ++mi)
            af[mi] = *(const bf16x8*)&Ac[(wm * 64 + mi * 16 + l15) * 32 + lq * 8];
#pragma unroll
        for (int ni = 0; ni < 4; ++ni)
            bf[ni] = *(const bf16x8*)&Bc[(wn * 64 + ni * 16 + l15) * 32 + lq * 8];
#pragma unroll
        for (int mi = 0; mi < 4; ++mi)
#pragma unroll
            for (int ni = 0; ni < 4; ++ni)
                acc[mi][ni] = __builtin_amdgcn_mfma_f32_16x16x32_bf16(
                    af[mi], bf[ni], acc[mi][ni], 0, 0, 0);
        cur ^= 1;
    }
}

// Kernel 1: QKV projection -> bf16 Qraw/Kraw/Vraw in [B,H,TN,DH].
// RoPE (+ the 0.125*log2e attention scale) folded into the Q epilogue.
__global__ __launch_bounds__(256) void gemm_qkv_mfma(
    const unsigned short* __restrict__ Xbf,
    const unsigned short* __restrict__ Wqkv,
    const float* __restrict__ bq, const float* __restrict__ bk,
    const float* __restrict__ bv, const float* __restrict__ inv_freq,
    const int* __restrict__ past_len,
    unsigned short* __restrict__ Qraw, unsigned short* __restrict__ Kraw,
    unsigned short* __restrict__ Vraw) {
    __shared__ __align__(16) short As[2 * 128 * 32];
    __shared__ __align__(16) short Bs[2 * 128 * 32];
    f32x4 acc[4][4] = {};
    const int m0 = blockIdx.y << 7, n0 = blockIdx.x << 7;
    gemm_core(Xbf, Wqkv, DM, m0, n0, As, Bs, acc);

    const int which = n0 >> 10;
    const int tid = threadIdx.x, wave = tid >> 6, lane = tid & 63;
    const int wm = wave >> 1, wn = wave & 1, l15 = lane & 15, lq = lane >> 4;

    if (which == 0) {
        // Q path with fused RoPE. 128-row tile sits in a single batch item.
        const int bb = m0 >> 9;
        const int pl = past_len[bb];
        const int hh = (n0 + wn * 64) >> 6;
#pragma unroll
        for (int ni = 0; ni < 2; ++ni) {
            int i = ni * 16 + l15;          // dh_lo in [0,32)
            int n1 = n0 + wn * 64 + ni * 16 + l15;
            float fi = inv_freq[i];
            float blo = bq[n1], bhi = bq[n1 + 32];
#pragma unroll
            for (int mi = 0; mi < 4; ++mi) {
#pragma unroll
                for (int r = 0; r < 4; ++r) {
                    int m = m0 + wm * 64 + mi * 16 + lq * 4 + r;
                    int t = m & 511;
                    float ang = (float)(pl + t) * fi;
                    float s, c;
                    __sincosf(ang, &s, &c);
                    float x1 = acc[mi][ni][r] + blo;
                    float x2 = acc[mi][ni + 2][r] + bhi;
                    size_t base = ((size_t)(bb * H_ + hh) * TN + t) * DH;
                    Qraw[base + i]      = f2b((x1 * c - x2 * s) * QSC);
                    Qraw[base + i + 32] = f2b((x2 * c + x1 * s) * QSC);
                }
            }
        }
    } else {
        const float* bias = which == 1 ? bk : bv;
        unsigned short* dst = which == 1 ? Kraw : Vraw;
#pragma unroll
        for (int ni = 0; ni < 4; ++ni) {
            int n1 = (n0 & 1023) + wn * 64 + ni * 16 + l15;
            float bb = bias[n1];
            int h = n1 >> 6, dh = n1 & 63;
#pragma unroll
            for (int mi = 0; mi < 4; ++mi) {
#pragma unroll
                for (int r = 0; r < 4; ++r) {
                    int m = m0 + wm * 64 + mi * 16 + lq * 4 + r;
                    int b = m >> 9, t = m & 511;
                    dst[((size_t)(b * H_ + h) * TN + t) * DH + dh] =
                        f2b(acc[mi][ni][r] + bb);
                }
            }
        }
    }
}

// Kernel 4: output projection, masked rows -> 0, f32 out.
__global__ __launch_bounds__(256) void gemm_out_mfma(
    const unsigned short* __restrict__ Ctxb,
    const unsigned short* __restrict__ Wob,
    const float* __restrict__ bo, const int* __restrict__ counts,
    float* __restrict__ Out) {
    __shared__ __align__(16) short As[2 * 128 * 32];
    __shared__ __align__(16) short Bs[2 * 128 * 32];
    f32x4 acc[4][4] = {};
    const int m0 = blockIdx.y << 7, n0 = blockIdx.x << 7;
    gemm_core(Ctxb, Wob, DM, m0, n0, As, Bs, acc);

    const int tid = threadIdx.x, wave = tid >> 6, lane = tid & 63;
    const int wm = wave >> 1, wn = wave & 1, l15 = lane & 15, lq = lane >> 4;
    const int cnt = counts[m0 >> 9];  // block-uniform batch item
#pragma unroll
    for (int mi = 0; mi < 4; ++mi) {
#pragma unroll
        for (int r = 0; r < 4; ++r) {
            int m = m0 + wm * 64 + mi * 16 + lq * 4 + r;
            int t = m & 511;
            bool valid = t < cnt;
#pragma unroll
            for (int ni = 0; ni < 4; ++ni) {
                int n = n0 + wn * 64 + ni * 16 + l15;
                Out[(size_t)m * DM + n] = valid ? acc[mi][ni][r] + bo[n] : 0.f;
            }
        }
    }
}

// ---------------------------------------------------------------------------
// Kernel 2b: build k_total / v_total (f32 outputs) + bf16 copies. Vectorized:
// 8 threads per position, each owns dh quads {4i..4i+3, 4i+32..4i+35}.
__global__ void build_kv(const float* __restrict__ past_k,
                         const float* __restrict__ past_v,
                         const unsigned short* __restrict__ Kraw,
                         const unsigned short* __restrict__ Vraw,
                         const float* __restrict__ inv_freq,
                         const int* __restrict__ past_len,
                         const int* __restrict__ counts,
                         float* __restrict__ Ko, float* __restrict__ Vo,
                         unsigned short* __restrict__ Kb16,
                         unsigned short* __restrict__ Vb16) {
    int idx = blockIdx.x * 256 + threadIdx.x;  // TT*8
    int i = idx & 7;
    int p = idx >> 3;
    int h = blockIdx.y, bz = blockIdx.z;
    int pl = past_len[bz], cnt = counts[bz];
    int dh = i << 2;
    size_t obase = ((size_t)(bz * H_ + h) * TT + p) * DH;
    F4 k1, k2, v1, v2;
    if (p < pl) {
        size_t ib = ((size_t)(bz * H_ + h) * CACHED_ + p) * DH;
        k1.v = *(const float4*)(past_k + ib + dh);
        k2.v = *(const float4*)(past_k + ib + dh + 32);
        v1.v = *(const float4*)(past_v + ib + dh);
        v2.v = *(const float4*)(past_v + ib + dh + 32);
    } else if (p < pl + cnt) {
        int t = p - pl;
        size_t ib = ((size_t)(bz * H_ + h) * TN + t) * DH;
        U16x4 ka, kc, va, vc;
        ka.u = *(const uint2*)(Kraw + ib + dh);
        kc.u = *(const uint2*)(Kraw + ib + dh + 32);
        va.u = *(const uint2*)(Vraw + ib + dh);
        vc.u = *(const uint2*)(Vraw + ib + dh + 32);
#pragma unroll
        for (int j = 0; j < 4; ++j) {
            float ang = (float)p * inv_freq[dh + j];
            float s, c;
            __sincosf(ang, &s, &c);
            float x1 = b2f(ka.s[j]), x2 = b2f(kc.s[j]);
            k1.f[j] = x1 * c - x2 * s;
            k2.f[j] = x2 * c + x1 * s;
            v1.f[j] = b2f(va.s[j]);
            v2.f[j] = b2f(vc.s[j]);
        }
    } else {
        k1.v = k2.v = v1.v = v2.v = make_float4(0.f, 0.f, 0.f, 0.f);
    }
    *(float4*)(Ko + obase + dh) = k1.v;
    *(float4*)(Ko + obase + dh + 32) = k2.v;
    *(float4*)(Vo + obase + dh) = v1.v;
    *(float4*)(Vo + obase + dh + 32) = v2.v;
    U16x4 o;
#pragma unroll
    for (int j = 0; j < 4; ++j) o.s[j] = f2b(k1.f[j]);
    *(uint2*)(Kb16 + obase + dh) = o.u;
#pragma unroll
    for (int j = 0; j < 4; ++j) o.s[j] = f2b(k2.f[j]);
    *(uint2*)(Kb16 + obase + dh + 32) = o.u;
#pragma unroll
    for (int j = 0; j < 4; ++j) o.s[j] = f2b(v1.f[j]);
    *(uint2*)(Vb16 + obase + dh) = o.u;
#pragma unroll
    for (int j = 0; j < 4; ++j) o.s[j] = f2b(v2.f[j]);
    *(uint2*)(Vb16 + obase + dh + 32) = o.u;
}

// ---------------------------------------------------------------------------
// Kernel 3: MFMA flash attention, 512 threads (8 waves), QBLK=128.
// EXACT R11-verified structure (496.2 us): two barriers per KV-tile,
// single Vt buffer, 2-phase K pipeline, cvt_pk P-store, no setprio
// (R13 isolated setprio: null). Split-K reverted (R14: L2 thrash,
// FETCH 38->517 MB -- the 2-blocks/CU qt-co-streaming IS the optimization).
__global__ __launch_bounds__(512) void attn_mfma(
    const unsigned short* __restrict__ Qbf,   // [B,H,TN,DH] bf16 (roped*QSC)
    const unsigned short* __restrict__ Kb,    // [B,H,TT,DH] bf16
    const unsigned short* __restrict__ Vb,    // [B,H,TT,DH] bf16
    const int* __restrict__ past_len, const int* __restrict__ counts,
    unsigned short* __restrict__ Ctxb) {      // [B,TN,DM] bf16
    // decode: j = xcd + 8*(qt + 4*pg), p = pg*8 + xcd  [bijective over 512]
    const int j = blockIdx.x;
    const int xcd = j & 7;
    const int tloc = j >> 3;                  // [0,64)
    const int qt = tloc & 3;                  // [0,4)
    const int p = ((tloc >> 2) << 3) | xcd;   // (b,h) pair in [0,128)
    const int b = p >> 4, h = p & 15;

    const int tid = threadIdx.x;              // [0,512)
    const int wave = tid >> 6, lane = tid & 63;
    const int l15 = lane & 15, lq = lane >> 4;

    __shared__ __align__(16) short Qs[8192];      // 128 x 64
    __shared__ __align__(16) short Ks[2][4096];   // 2 x (64 x 64)
    __shared__ __align__(16) short Vt[4096];      // 64dh x 64k transposed
    __shared__ __align__(16) short Pb[8192];      // 8 waves x (16 x 64)

    const size_t qbase = ((size_t)(b * H_ + h) * TN + qt * 128) * DH;
    const size_t kbase = (size_t)(b * H_ + h) * TT * DH;

    const int total = past_len[b] + counts[b];
    const int ntiles = (total + 63) >> 6;

    // async K staging: 512 dest chunks, 1/thread. dest chunk d -> src:
    // g=d>>7, c=(d>>4)&7, row=g*16+((d&15)^c), col=c*8
    const int dA = tid;
    const int krA = (dA >> 7) * 16 + ((dA & 15) ^ ((dA >> 4) & 7));
    const int kcA = ((dA >> 4) & 7) << 3;
    const unsigned short* KgA = Kb + kbase + (size_t)krA * DH + kcA;
    const int kdoffA = wave * 512;            // wave-uniform LDS short-offset

    // prefetch K tile 0 (latency covered by Q staging below)
    gload16(KgA, &Ks[0][kdoffA]);

    // V: thread owns keys {2kp,2kp+1} x 4 dh values (uint2 loads)
    const int kp = tid & 31;
    const int dh4 = (tid >> 5) << 2;          // [0,64) step 4
    const int kc = kp >> 2, ko2 = (kp & 3) << 1;
    const unsigned short* Vg = Vb + kbase + (size_t)(2 * kp) * DH + dh4;
    uint2 vr0 = *(const uint2*)Vg;            // tile 0 prefetch
    uint2 vr1 = *(const uint2*)(Vg + DH);

    // stage Q (swizzled, one-time reg path): 1024 chunks, 2/thread
#pragma unroll
    for (int jj = 0; jj < 2; ++jj) {
        int e = tid + (jj << 9);
        int row = e >> 3, c = e & 7;
        *(uint4*)&Qs[(((row >> 4) * 8 + c) * 16 + ((row & 15) ^ c)) * 8] =
            *(const uint4*)(Qbf + qbase + row * 64 + c * 8);
    }
    __syncthreads();   // prologue: drains everything incl. K(0)/V(0)
    const int c0 = lq, c1 = 4 + lq;
    bf16x8 qa0 = *(const bf16x8*)&Qs[((wave * 8 + c0) * 16 + (l15 ^ c0)) * 8];
    bf16x8 qa1 = *(const bf16x8*)&Qs[((wave * 8 + c1) * 16 + (l15 ^ c1)) * 8];

    float rsum[4] = {0.f, 0.f, 0.f, 0.f};
    f32x4 O[4] = {};
    unsigned short* Pw = (unsigned short*)(Pb + wave * 1024);
    const int pc0 = l15 >> 3, pwo = l15 & 7;

    int cur = 0;
    for (int kt = 0; kt < ntiles; ++kt) {
        // --- barrier A: prefetched K(kt)+V(kt) complete; all waves done
        //     reading previous tile's Ks[cur^1] and Vt.
        asm volatile("s_waitcnt vmcnt(0)" ::: "memory");
        __builtin_amdgcn_s_barrier();

        // V(kt) regs -> Vt (swizzled transpose write, 4 dh per thread)
        {
            U16x4 a, cc;
            a.u = vr0;
            cc.u = vr1;
#pragma unroll
            for (int jj = 0; jj < 4; ++jj) {
                int dh = dh4 + jj;
                unsigned pk = (unsigned)a.s[jj] | ((unsigned)cc.s[jj] << 16);
                *(unsigned*)&Vt[((((dh >> 4) * 8 + kc) * 16) + ((dh & 15) ^ kc)) * 8 + ko2] = pk;
            }
        }
        // prefetch tile kt+1 (clamped): K -> Ks[cur^1] (async LDS),
        // V -> regs. In flight across the whole compute phase below.
        {
            int ktn = (kt + 1 < ntiles) ? kt + 1 : kt;
            gload16(KgA + (size_t)ktn * 64 * DH, &Ks[cur ^ 1][kdoffA]);
            vr0 = *(const uint2*)(Vg + (size_t)ktn * 64 * DH);
            vr1 = *(const uint2*)(Vg + (size_t)ktn * 64 * DH + DH);
        }

        // --- barrier D: publish V ds_writes; do NOT drain vmem prefetch.
        asm volatile("s_waitcnt lgkmcnt(0)" ::: "memory");
        __builtin_amdgcn_s_barrier();
        __builtin_amdgcn_sched_barrier(0);

        // S = Q K^T from Ks[cur] (scale + log2e pre-folded into Q)
        const short* Kcur = Ks[cur];
        f32x4 S[4];
#pragma unroll
        for (int nt = 0; nt < 4; ++nt) {
            f32x4 acc = {};
            bf16x8 kb0 = *(const bf16x8*)&Kcur[((nt * 8 + c0) * 16 + (l15 ^ c0)) * 8];
            acc = __builtin_amdgcn_mfma_f32_16x16x32_bf16(qa0, kb0, acc, 0, 0, 0);
            bf16x8 kb1 = *(const bf16x8*)&Kcur[((nt * 8 + c1) * 16 + (l15 ^ c1)) * 8];
            acc = __builtin_amdgcn_mfma_f32_16x16x32_bf16(qa1, kb1, acc, 0, 0, 0);
            S[nt] = acc;
        }

        // mask only the (uniform) last partial tile
        int limit = total - (kt << 6);
        if (limit < 64) {
#pragma unroll
            for (int nt = 0; nt < 4; ++nt) {
                bool ok = nt * 16 + l15 < limit;
#pragma unroll
                for (int r = 0; r < 4; ++r) S[nt][r] = ok ? S[nt][r] : -1e30f;
            }
        }

        // P = exp2(S); per-lane partial row sums; bf16 P via cvt_pk pairs.
#pragma unroll
        for (int nt = 0; nt < 4; ++nt) {
            const int pc = nt * 2 + pc0;
#pragma unroll
            for (int rr = 0; rr < 2; ++rr) {
                float p0 = __builtin_amdgcn_exp2f(S[nt][2 * rr]);
                float p1 = __builtin_amdgcn_exp2f(S[nt][2 * rr + 1]);
                rsum[2 * rr] += p0;
                rsum[2 * rr + 1] += p1;
                unsigned pk = cvt_pk_bf16(p0, p1);
                int row0 = lq * 4 + 2 * rr;
                int row1 = row0 + 1;
                Pw[(pc * 16 + (row0 ^ pc)) * 8 + pwo] = (unsigned short)pk;
                Pw[(pc * 16 + (row1 ^ pc)) * 8 + pwo] = (unsigned short)(pk >> 16);
            }
        }
        asm volatile("s_waitcnt lgkmcnt(0)" ::: "memory");

        // O += P V
        bf16x8 pa0 = *(const bf16x8*)&Pw[(c0 * 16 + (l15 ^ c0)) * 8];
        bf16x8 pa1 = *(const bf16x8*)&Pw[(c1 * 16 + (l15 ^ c1)) * 8];
#pragma unroll
        for (int nt = 0; nt < 4; ++nt) {
            bf16x8 vb0 = *(const bf16x8*)&Vt[((nt * 8 + c0) * 16 + (l15 ^ c0)) * 8];
            O[nt] = __builtin_amdgcn_mfma_f32_16x16x32_bf16(pa0, vb0, O[nt], 0, 0, 0);
            bf16x8 vb1 = *(const bf16x8*)&Vt[((nt * 8 + c1) * 16 + (l15 ^ c1)) * 8];
            O[nt] = __builtin_amdgcn_mfma_f32_16x16x32_bf16(pa1, vb1, O[nt], 0, 0, 0);
        }
        cur ^= 1;
    }

    // one-time l reduction across the 16 key-lanes
#pragma unroll
    for (int off = 1; off < 16; off <<= 1)
#pragma unroll
        for (int r = 0; r < 4; ++r) rsum[r] += __shfl_xor(rsum[r], off);

    // epilogue: ctx/l -> bf16 [B,TN,DM] (m = b*TN+t, k = h*64+dh)
#pragma unroll
    for (int r = 0; r < 4; ++r) {
        float inv = 1.f / rsum[r];
        int t = qt * 128 + wave * 16 + lq * 4 + r;
        size_t mbase = ((size_t)(b * TN + t)) * DM + h * DH;
#pragma unroll
        for (int nt = 0; nt < 4; ++nt)
            Ctxb[mbase + nt * 16 + l15] = f2b(O[nt][r] * inv);
    }
}

// ---------------------------------------------------------------------------
extern "C" void kernel_launch(void* const* d_in, const int* in_sizes, int n_in,
                              void* d_out, int out_size, void* d_ws, size_t ws_size,
                              hipStream_t stream) {
    const float* x_new    = (const float*)d_in[0];
    const float* inv_freq = (const float*)d_in[1];
    const float* past_k   = (const float*)d_in[2];
    const float* past_v   = (const float*)d_in[3];
    const float* Wq = (const float*)d_in[4];
    const float* bq = (const float*)d_in[5];
    const float* Wk = (const float*)d_in[6];
    const float* bk = (const float*)d_in[7];
    const float* Wv = (const float*)d_in[8];
    const float* bv = (const float*)d_in[9];
    const float* Wo = (const float*)d_in[10];
    const float* bo = (const float*)d_in[11];
    const unsigned char* kpm = (const unsigned char*)d_in[12];
    const int* past_len      = (const int*)d_in[13];
    const unsigned char* vnm = (const unsigned char*)d_in[14];

    float* out      = (float*)d_out;                         // [B,TN,DM]
    float* k_total  = out + (size_t)B_ * TN * DM;            // [B,H,TT,DH]
    float* v_total  = k_total + (size_t)B_ * H_ * TT * DH;
    float* total_out = v_total + (size_t)B_ * H_ * TT * DH;  // [B] (float)

    const size_t NQ = (size_t)B_ * TN * DM;        // 4M
    const size_t NKV = (size_t)B_ * H_ * TT * DH;  // 21M

    int* counts = (int*)d_ws;
    unsigned short* Xbf   = (unsigned short*)((char*)d_ws + 256);  // [4096,1024]
    unsigned short* Wqkvb = Xbf + NQ;                              // [3072,1024]
    unsigned short* Wob   = Wqkvb + (size_t)3 * DM * DM;           // [1024,1024]
    unsigned short* Qraw  = Wob + (size_t)DM * DM;                 // [B,H,TN,DH]
    unsigned short* Kraw  = Qraw + NQ;
    unsigned short* Vraw  = Kraw + NQ;
    unsigned short* Ctxb  = Vraw + NQ;                             // [B,TN,DM]
    unsigned short* Kb16  = Ctxb + NQ;                             // [B,H,TT,DH]
    unsigned short* Vb16  = Kb16 + NKV;

    cvt_all<<<4104, 256, 0, stream>>>(x_new, Wq, Wk, Wv, Wo, Xbf, Wqkvb, Wob,
                                      vnm, kpm, past_len, counts, total_out);

    gemm_qkv_mfma<<<dim3(24, 32), 256, 0, stream>>>(
        Xbf, Wqkvb, bq, bk, bv, inv_freq, past_len, Qraw, Kraw, Vraw);
    build_kv<<<dim3((TT * 8) / 256, H_, B_), 256, 0, stream>>>(
        past_k, past_v, Kraw, Vraw, inv_freq, past_len, counts,
        k_total, v_total, Kb16, Vb16);
    attn_mfma<<<512, 512, 0, stream>>>(Qraw, Kb16, Vb16,
                                       past_len, counts, Ctxb);
    gemm_out_mfma<<<dim3(8, 32), 256, 0, stream>>>(Ctxb, Wob, bo, counts, out);
}